// Round 13
// baseline (75.780 us; speedup 1.0000x reference)
//
#include <hip/hip_runtime.h>
#include <hip/hip_bf16.h>

// PolymorphicSNN: reference collapses to
//   out[:, :256]     = heaviside(x @ W_lin.T + b_lin - 1.0)
//   out[:, 256:8448] = 0    (spk_mode == 0 identically since reg_out in {0,1})
//
// Finding (R2..R12): any wave mixing compute + bulk stores caps at ~4.8 TB/s;
// pure-store dispatch (rocclr fill) sustains 6.9 TB/s. So: THREE dispatches,
// each in its pure regime:
//   1. WT transpose (tiny)
//   2. GEMM + spikes + 64 MB of fill (what ~12 us of compute hides for free
//      at the mixed ceiling) -- exactly the 59.9-us kernel minus half its
//      stores (covers fill cols 0..511 of each row)
//   3. pure fill kernel: remaining 201 MB (cols 512..2047) at the pure rate.

#define SNN_B 8192
#define SNN_N 256
#define SNN_P 32
#define SNN_ROW (SNN_N * (SNN_P + 1))   // 8448 floats per output row
#define BLK_ROWS 16                     // batch rows per GEMM block (4/wave)

// ---- Pre-pass: W_T[k][n] = W[n][k] (256x256) ----
__global__ __launch_bounds__(256) void w_transpose_kernel(
    const float* __restrict__ W, float* __restrict__ WT)
{
    const int o = blockIdx.x * 256 + threadIdx.x;   // coalesced write
    const int k = o >> 8, n = o & 255;
    WT[o] = W[n * SNN_N + k];
}

// ---- Pure fill: zero cols [512,2048) of every row's fill region (201 MB) ----
__global__ __launch_bounds__(256) void fill_kernel(float* __restrict__ out)
{
    const int tid  = threadIdx.x;
    const int row0 = blockIdx.x * 4;                 // 2048 blocks x 4 rows
    const float4 z = make_float4(0.f, 0.f, 0.f, 0.f);
#pragma unroll
    for (int r = 0; r < 4; ++r) {
        float4* o4 = reinterpret_cast<float4*>(
                         out + (size_t)(row0 + r) * SNN_ROW + SNN_N) + 512;
#pragma unroll
        for (int j = 0; j < 6; ++j) {                // 1536 float4 per row
            o4[j * 256 + tid] = z;
        }
    }
}

// ---- GEMM + spikes + fill cols [0,512) (the 59.9-us kernel, half stores) ----
__global__ __launch_bounds__(256) void polysnn_main_kernel(
    const float* __restrict__ x,      // [B, N]
    const float* __restrict__ W,      // [N, N] original (borderline recheck only)
    const float* __restrict__ WT,     // [N, N] transposed: WT[k][n]
    const float* __restrict__ bias,   // [N]
    float* __restrict__ out)          // [B, 8448]
{
    __shared__ float xs[BLK_ROWS][SNN_N];

    const int tid  = threadIdx.x;
    const int lane = tid & 63;
    const int wave = tid >> 6;
    const int row0 = blockIdx.x * BLK_ROWS;

    // Stage 16 x-rows (16 KB): 1024 float4, 4 per thread.
    {
        const float4* x4  = reinterpret_cast<const float4*>(x + (size_t)row0 * SNN_N);
        float4*       xsw = reinterpret_cast<float4*>(&xs[0][0]);
#pragma unroll
        for (int i = 0; i < 4; ++i) xsw[tid + i * 256] = x4[tid + i * 256];
    }
    __syncthreads();

    // Wave handles rows grow0..+3; lane owns cols 4*lane..4*lane+3.
    const int grow0 = row0 + wave * 4;
    const float4* wt4 = reinterpret_cast<const float4*>(WT);   // [k][64 float4]
    const float4* xs4 = reinterpret_cast<const float4*>(&xs[0][0]);
    const int xbase = wave * 4 * 64;

    float acc[4][4];
#pragma unroll
    for (int r = 0; r < 4; ++r)
#pragma unroll
        for (int c = 0; c < 4; ++c) acc[r][c] = 0.0f;

    float4 wcur0 = wt4[0 * 64 + lane];
    float4 wcur1 = wt4[1 * 64 + lane];
    float4 wcur2 = wt4[2 * 64 + lane];
    float4 wcur3 = wt4[3 * 64 + lane];
    float4 xcur[4];
#pragma unroll
    for (int r = 0; r < 4; ++r) xcur[r] = xs4[xbase + r * 64 + 0];

    float* const wfill = out + (size_t)grow0 * SNN_ROW;  // wave's first out row
    const float4 z = make_float4(0.f, 0.f, 0.f, 0.f);

#pragma unroll 2
    for (int i = 0; i < 64; ++i) {
        // ---- prefetch next iteration (wrap at end; redundant last loads) ----
        const int ip = (i + 1) & 63;
        float4 wnx0 = wt4[(ip * 4 + 0) * 64 + lane];
        float4 wnx1 = wt4[(ip * 4 + 1) * 64 + lane];
        float4 wnx2 = wt4[(ip * 4 + 2) * 64 + lane];
        float4 wnx3 = wt4[(ip * 4 + 3) * 64 + lane];
        float4 xnxt[4];
#pragma unroll
        for (int r = 0; r < 4; ++r) xnxt[r] = xs4[xbase + r * 64 + ip];

        // ---- fill cols [0,512) of our 4 rows: 1 store per 2 iters ----
        if ((i & 1) == 0) {
            const int fidx = ((i >> 1) << 6) + lane;   // 0..2047
            const int rl   = fidx >> 9;                // 512 float4 per row here
            const int c4   = fidx & 511;
            *reinterpret_cast<float4*>(wfill + rl * SNN_ROW + SNN_N + (c4 << 2)) = z;
        }

        // ---- compute iter i: 64 FMAs ----
#pragma unroll
        for (int r = 0; r < 4; ++r) {
            const float4 xr = xcur[r];
            acc[r][0] = fmaf(xr.x, wcur0.x, acc[r][0]);
            acc[r][1] = fmaf(xr.x, wcur0.y, acc[r][1]);
            acc[r][2] = fmaf(xr.x, wcur0.z, acc[r][2]);
            acc[r][3] = fmaf(xr.x, wcur0.w, acc[r][3]);
            acc[r][0] = fmaf(xr.y, wcur1.x, acc[r][0]);
            acc[r][1] = fmaf(xr.y, wcur1.y, acc[r][1]);
            acc[r][2] = fmaf(xr.y, wcur1.z, acc[r][2]);
            acc[r][3] = fmaf(xr.y, wcur1.w, acc[r][3]);
            acc[r][0] = fmaf(xr.z, wcur2.x, acc[r][0]);
            acc[r][1] = fmaf(xr.z, wcur2.y, acc[r][1]);
            acc[r][2] = fmaf(xr.z, wcur2.z, acc[r][2]);
            acc[r][3] = fmaf(xr.z, wcur2.w, acc[r][3]);
            acc[r][0] = fmaf(xr.w, wcur3.x, acc[r][0]);
            acc[r][1] = fmaf(xr.w, wcur3.y, acc[r][1]);
            acc[r][2] = fmaf(xr.w, wcur3.z, acc[r][2]);
            acc[r][3] = fmaf(xr.w, wcur3.w, acc[r][3]);
        }

        wcur0 = wnx0; wcur1 = wnx1; wcur2 = wnx2; wcur3 = wnx3;
#pragma unroll
        for (int r = 0; r < 4; ++r) xcur[r] = xnxt[r];
    }

    // ---- epilogue: bias, threshold, rare f64 recheck, coalesced spike store ----
    const float4 bb = reinterpret_cast<const float4*>(bias)[lane];
#pragma unroll
    for (int r = 0; r < 4; ++r) {
        float h[4] = {acc[r][0] + bb.x, acc[r][1] + bb.y,
                      acc[r][2] + bb.z, acc[r][3] + bb.w};
        float s[4];
#pragma unroll
        for (int c = 0; c < 4; ++c) {
            if (__builtin_expect(fabsf(h[c] - 1.0f) < 1e-3f, 0)) {
                // Borderline (f32 accum error <= ~6e-5 << 1e-3): f64 recheck.
                const int n = 4 * lane + c;
                double a = (double)bias[n];
                const float* wr = W + (size_t)n * SNN_N;
                for (int k = 0; k < SNN_N; ++k)
                    a += (double)wr[k] * (double)xs[wave * 4 + r][k];
                s[c] = (a > 1.0) ? 1.0f : 0.0f;
            } else {
                s[c] = (h[c] > 1.0f) ? 1.0f : 0.0f;
            }
        }
        *reinterpret_cast<float4*>(out + (size_t)(grow0 + r) * SNN_ROW + (lane << 2))
            = make_float4(s[0], s[1], s[2], s[3]);
    }
}

// ---- Fallback (ws too small): round-2 monolithic kernel (69 us, absmax 0) ----
__global__ __launch_bounds__(256) void polysnn_mono_kernel(
    const float* __restrict__ x, const float* __restrict__ W,
    const float* __restrict__ bias, float* __restrict__ out)
{
    __shared__ float xs[8][SNN_N];
    const int tid = threadIdx.x;
    const int row0 = blockIdx.x * 8;
    {
        const float4* x4  = reinterpret_cast<const float4*>(x + (size_t)row0 * SNN_N);
        float4*       xsw = reinterpret_cast<float4*>(&xs[0][0]);
        xsw[tid] = x4[tid]; xsw[tid + 256] = x4[tid + 256];
    }
    __syncthreads();
    const float4 zz = make_float4(0.f, 0.f, 0.f, 0.f);
#pragma unroll
    for (int r = 0; r < 8; ++r) {
        float4* o4 = reinterpret_cast<float4*>(out + (size_t)(row0 + r) * SNN_ROW + SNN_N);
#pragma unroll
        for (int i = 0; i < 8; ++i) o4[tid + i * 256] = zz;
    }
    const int n = tid;
    float acc[8];
#pragma unroll
    for (int r = 0; r < 8; ++r) acc[r] = 0.0f;
    const float4* w4  = reinterpret_cast<const float4*>(W + (size_t)n * SNN_N);
    const float4* xs4 = reinterpret_cast<const float4*>(&xs[0][0]);
#pragma unroll 4
    for (int k4 = 0; k4 < SNN_N / 4; ++k4) {
        const float4 w = w4[k4];
#pragma unroll
        for (int r = 0; r < 8; ++r) {
            const float4 xr = xs4[r * 64 + k4];
            acc[r] = fmaf(w.x, xr.x, acc[r]); acc[r] = fmaf(w.y, xr.y, acc[r]);
            acc[r] = fmaf(w.z, xr.z, acc[r]); acc[r] = fmaf(w.w, xr.w, acc[r]);
        }
    }
    const float bn = bias[n];
#pragma unroll
    for (int r = 0; r < 8; ++r) {
        const float h = acc[r] + bn;
        float spike;
        if (__builtin_expect(fabsf(h - 1.0f) < 1e-3f, 0)) {
            double a = (double)bn;
            const float* wr = W + (size_t)n * SNN_N;
            for (int k = 0; k < SNN_N; ++k) a += (double)wr[k] * (double)xs[r][k];
            spike = (a > 1.0) ? 1.0f : 0.0f;
        } else spike = (h > 1.0f) ? 1.0f : 0.0f;
        out[(size_t)(row0 + r) * SNN_ROW + n] = spike;
    }
}

extern "C" void kernel_launch(void* const* d_in, const int* in_sizes, int n_in,
                              void* d_out, int out_size, void* d_ws, size_t ws_size,
                              hipStream_t stream) {
    const float* x     = (const float*)d_in[0];
    const float* W_lin = (const float*)d_in[1];
    const float* b_lin = (const float*)d_in[2];
    // d_in[3] (W_sel) and d_in[4] (b_sel) are dead: spk_mode == 0 identically.
    float* out = (float*)d_out;

    if (ws_size >= (size_t)SNN_N * SNN_N * sizeof(float)) {
        float* WT = (float*)d_ws;
        w_transpose_kernel<<<256, 256, 0, stream>>>(W_lin, WT);
        polysnn_main_kernel<<<SNN_B / BLK_ROWS, 256, 0, stream>>>(x, W_lin, WT, b_lin, out);
        fill_kernel<<<SNN_B / 4, 256, 0, stream>>>(out);
    } else {
        polysnn_mono_kernel<<<SNN_B / 8, 256, 0, stream>>>(x, W_lin, b_lin, out);
    }
}

// Round 14
// 59.100 us; speedup vs baseline: 1.2822x; 1.2822x over previous
//
#include <hip/hip_runtime.h>
#include <hip/hip_bf16.h>

// PolymorphicSNN: reference collapses to
//   out[:, :256]     = heaviside(x @ W_lin.T + b_lin - 1.0)
//   out[:, 256:8448] = 0    (spk_mode == 0 identically since reg_out in {0,1})
//
// Best so far: R9 = 59.9 us (single kernel, WT-transposed coalesced W loads,
// 512 blocks x 4 waves, 4 rows/wave, 2 fill stores interleaved per k-iter,
// regular cached stores). Store floor = 268 MB @ 6.9 TB/s = 39 us; residual
// ~20 us attributed to depth-1 prefetch exposing L1/L2 load latency each
// iter (only 2 waves/SIMD to cover it).
// This round: SAME structure + hand-written depth-2 prefetch (named A/B
// register sets, static indexing, NO unroll pragma -- R13's pragma-unroll
// spilled). 2 k-iters per body; loads issued one full body (~300 cyc)
// before use.

#define SNN_B 8192
#define SNN_N 256
#define SNN_P 32
#define SNN_ROW (SNN_N * (SNN_P + 1))   // 8448 floats per output row
#define BLK_ROWS 16                     // batch rows per block (4 per wave)

// ---- Pre-pass: W_T[k][n] = W[n][k] (256x256) ----
__global__ __launch_bounds__(256) void w_transpose_kernel(
    const float* __restrict__ W, float* __restrict__ WT)
{
    const int o = blockIdx.x * 256 + threadIdx.x;   // coalesced write
    const int k = o >> 8, n = o & 255;
    WT[o] = W[n * SNN_N + k];
}

// ---- Main: GEMM + spikes + interleaved zero-fill, depth-2 prefetch ----
__global__ __launch_bounds__(256) void polysnn_main_kernel(
    const float* __restrict__ x,      // [B, N]
    const float* __restrict__ W,      // [N, N] original (borderline recheck only)
    const float* __restrict__ WT,     // [N, N] transposed: WT[k][n]
    const float* __restrict__ bias,   // [N]
    float* __restrict__ out)          // [B, 8448]
{
    __shared__ float xs[BLK_ROWS][SNN_N];

    const int tid  = threadIdx.x;
    const int lane = tid & 63;
    const int wave = tid >> 6;
    const int row0 = blockIdx.x * BLK_ROWS;

    // Stage 16 x-rows (16 KB): 1024 float4, 4 per thread.
    {
        const float4* x4  = reinterpret_cast<const float4*>(x + (size_t)row0 * SNN_N);
        float4*       xsw = reinterpret_cast<float4*>(&xs[0][0]);
#pragma unroll
        for (int i = 0; i < 4; ++i) xsw[tid + i * 256] = x4[tid + i * 256];
    }
    __syncthreads();

    // Wave handles rows grow0..+3; lane owns cols 4*lane..4*lane+3.
    const int grow0 = row0 + wave * 4;
    const float4* wt4 = reinterpret_cast<const float4*>(WT);   // [k][64 float4]
    const float4* xs4 = reinterpret_cast<const float4*>(&xs[0][0]);
    const int xbase = wave * 4 * 64;

    float acc[4][4];
#pragma unroll
    for (int r = 0; r < 4; ++r)
#pragma unroll
        for (int c = 0; c < 4; ++c) acc[r][c] = 0.0f;

    // Depth-2 prefetch: set A = even iter, set B = odd iter.
    float4 wA0 = wt4[(0 * 4 + 0) * 64 + lane];
    float4 wA1 = wt4[(0 * 4 + 1) * 64 + lane];
    float4 wA2 = wt4[(0 * 4 + 2) * 64 + lane];
    float4 wA3 = wt4[(0 * 4 + 3) * 64 + lane];
    float4 wB0 = wt4[(1 * 4 + 0) * 64 + lane];
    float4 wB1 = wt4[(1 * 4 + 1) * 64 + lane];
    float4 wB2 = wt4[(1 * 4 + 2) * 64 + lane];
    float4 wB3 = wt4[(1 * 4 + 3) * 64 + lane];
    float4 xA[4], xB[4];
#pragma unroll
    for (int r = 0; r < 4; ++r) {
        xA[r] = xs4[xbase + r * 64 + 0];
        xB[r] = xs4[xbase + r * 64 + 1];
    }

    float* const wfill = out + (size_t)grow0 * SNN_ROW;  // wave's first out row
    const float4 z = make_float4(0.f, 0.f, 0.f, 0.f);

    for (int body = 0; body < 32; ++body) {
        const int i0  = body * 2;
        const int ipA = (i0 + 2) & 63;     // prefetch targets (wrap: redundant)
        const int ipB = (i0 + 3) & 63;

        // ---- issue prefetch for iters i0+2 / i0+3 (used NEXT body) ----
        float4 tA0 = wt4[(ipA * 4 + 0) * 64 + lane];
        float4 tA1 = wt4[(ipA * 4 + 1) * 64 + lane];
        float4 tA2 = wt4[(ipA * 4 + 2) * 64 + lane];
        float4 tA3 = wt4[(ipA * 4 + 3) * 64 + lane];
        float4 tB0 = wt4[(ipB * 4 + 0) * 64 + lane];
        float4 tB1 = wt4[(ipB * 4 + 1) * 64 + lane];
        float4 tB2 = wt4[(ipB * 4 + 2) * 64 + lane];
        float4 tB3 = wt4[(ipB * 4 + 3) * 64 + lane];
        float4 xtA[4], xtB[4];
#pragma unroll
        for (int r = 0; r < 4; ++r) {
            xtA[r] = xs4[xbase + r * 64 + ipA];
            xtB[r] = xs4[xbase + r * 64 + ipB];
        }

        // ---- interleaved zero-fill: 4 stores per body ----
#pragma unroll
        for (int j = 0; j < 4; ++j) {
            const int fidx = ((body * 4 + j) << 6) + lane;   // 0..8191
            const int rl   = fidx >> 11;          // 2048 float4 per row
            const int c4   = fidx & 2047;
            *reinterpret_cast<float4*>(wfill + rl * SNN_ROW + SNN_N + (c4 << 2)) = z;
        }

        // ---- compute iter i0 (set A) ----
#pragma unroll
        for (int r = 0; r < 4; ++r) {
            const float4 xr = xA[r];
            acc[r][0] = fmaf(xr.x, wA0.x, acc[r][0]);
            acc[r][1] = fmaf(xr.x, wA0.y, acc[r][1]);
            acc[r][2] = fmaf(xr.x, wA0.z, acc[r][2]);
            acc[r][3] = fmaf(xr.x, wA0.w, acc[r][3]);
            acc[r][0] = fmaf(xr.y, wA1.x, acc[r][0]);
            acc[r][1] = fmaf(xr.y, wA1.y, acc[r][1]);
            acc[r][2] = fmaf(xr.y, wA1.z, acc[r][2]);
            acc[r][3] = fmaf(xr.y, wA1.w, acc[r][3]);
            acc[r][0] = fmaf(xr.z, wA2.x, acc[r][0]);
            acc[r][1] = fmaf(xr.z, wA2.y, acc[r][1]);
            acc[r][2] = fmaf(xr.z, wA2.z, acc[r][2]);
            acc[r][3] = fmaf(xr.z, wA2.w, acc[r][3]);
            acc[r][0] = fmaf(xr.w, wA3.x, acc[r][0]);
            acc[r][1] = fmaf(xr.w, wA3.y, acc[r][1]);
            acc[r][2] = fmaf(xr.w, wA3.z, acc[r][2]);
            acc[r][3] = fmaf(xr.w, wA3.w, acc[r][3]);
        }
        // ---- compute iter i0+1 (set B) ----
#pragma unroll
        for (int r = 0; r < 4; ++r) {
            const float4 xr = xB[r];
            acc[r][0] = fmaf(xr.x, wB0.x, acc[r][0]);
            acc[r][1] = fmaf(xr.x, wB0.y, acc[r][1]);
            acc[r][2] = fmaf(xr.x, wB0.z, acc[r][2]);
            acc[r][3] = fmaf(xr.x, wB0.w, acc[r][3]);
            acc[r][0] = fmaf(xr.y, wB1.x, acc[r][0]);
            acc[r][1] = fmaf(xr.y, wB1.y, acc[r][1]);
            acc[r][2] = fmaf(xr.y, wB1.z, acc[r][2]);
            acc[r][3] = fmaf(xr.y, wB1.w, acc[r][3]);
            acc[r][0] = fmaf(xr.z, wB2.x, acc[r][0]);
            acc[r][1] = fmaf(xr.z, wB2.y, acc[r][1]);
            acc[r][2] = fmaf(xr.z, wB2.z, acc[r][2]);
            acc[r][3] = fmaf(xr.z, wB2.w, acc[r][3]);
            acc[r][0] = fmaf(xr.w, wB3.x, acc[r][0]);
            acc[r][1] = fmaf(xr.w, wB3.y, acc[r][1]);
            acc[r][2] = fmaf(xr.w, wB3.z, acc[r][2]);
            acc[r][3] = fmaf(xr.w, wB3.w, acc[r][3]);
        }

        // ---- rotate prefetch sets (static, no runtime indexing) ----
        wA0 = tA0; wA1 = tA1; wA2 = tA2; wA3 = tA3;
        wB0 = tB0; wB1 = tB1; wB2 = tB2; wB3 = tB3;
#pragma unroll
        for (int r = 0; r < 4; ++r) { xA[r] = xtA[r]; xB[r] = xtB[r]; }
    }

    // ---- epilogue: bias, threshold, rare f64 recheck, coalesced spike store ----
    const float4 bb = reinterpret_cast<const float4*>(bias)[lane];
#pragma unroll
    for (int r = 0; r < 4; ++r) {
        float h[4] = {acc[r][0] + bb.x, acc[r][1] + bb.y,
                      acc[r][2] + bb.z, acc[r][3] + bb.w};
        float s[4];
#pragma unroll
        for (int c = 0; c < 4; ++c) {
            if (__builtin_expect(fabsf(h[c] - 1.0f) < 1e-3f, 0)) {
                // Borderline (f32 accum error <= ~6e-5 << 1e-3): f64 recheck.
                const int n = 4 * lane + c;
                double a = (double)bias[n];
                const float* wr = W + (size_t)n * SNN_N;
                for (int k = 0; k < SNN_N; ++k)
                    a += (double)wr[k] * (double)xs[wave * 4 + r][k];
                s[c] = (a > 1.0) ? 1.0f : 0.0f;
            } else {
                s[c] = (h[c] > 1.0f) ? 1.0f : 0.0f;
            }
        }
        *reinterpret_cast<float4*>(out + (size_t)(grow0 + r) * SNN_ROW + (lane << 2))
            = make_float4(s[0], s[1], s[2], s[3]);
    }
}

// ---- Fallback (ws too small): round-2 monolithic kernel (69 us, absmax 0) ----
__global__ __launch_bounds__(256) void polysnn_mono_kernel(
    const float* __restrict__ x, const float* __restrict__ W,
    const float* __restrict__ bias, float* __restrict__ out)
{
    __shared__ float xs[8][SNN_N];
    const int tid = threadIdx.x;
    const int row0 = blockIdx.x * 8;
    {
        const float4* x4  = reinterpret_cast<const float4*>(x + (size_t)row0 * SNN_N);
        float4*       xsw = reinterpret_cast<float4*>(&xs[0][0]);
        xsw[tid] = x4[tid]; xsw[tid + 256] = x4[tid + 256];
    }
    __syncthreads();
    const float4 zz = make_float4(0.f, 0.f, 0.f, 0.f);
#pragma unroll
    for (int r = 0; r < 8; ++r) {
        float4* o4 = reinterpret_cast<float4*>(out + (size_t)(row0 + r) * SNN_ROW + SNN_N);
#pragma unroll
        for (int i = 0; i < 8; ++i) o4[tid + i * 256] = zz;
    }
    const int n = tid;
    float acc[8];
#pragma unroll
    for (int r = 0; r < 8; ++r) acc[r] = 0.0f;
    const float4* w4  = reinterpret_cast<const float4*>(W + (size_t)n * SNN_N);
    const float4* xs4 = reinterpret_cast<const float4*>(&xs[0][0]);
#pragma unroll 4
    for (int k4 = 0; k4 < SNN_N / 4; ++k4) {
        const float4 w = w4[k4];
#pragma unroll
        for (int r = 0; r < 8; ++r) {
            const float4 xr = xs4[r * 64 + k4];
            acc[r] = fmaf(w.x, xr.x, acc[r]); acc[r] = fmaf(w.y, xr.y, acc[r]);
            acc[r] = fmaf(w.z, xr.z, acc[r]); acc[r] = fmaf(w.w, xr.w, acc[r]);
        }
    }
    const float bn = bias[n];
#pragma unroll
    for (int r = 0; r < 8; ++r) {
        const float h = acc[r] + bn;
        float spike;
        if (__builtin_expect(fabsf(h - 1.0f) < 1e-3f, 0)) {
            double a = (double)bn;
            const float* wr = W + (size_t)n * SNN_N;
            for (int k = 0; k < SNN_N; ++k) a += (double)wr[k] * (double)xs[r][k];
            spike = (a > 1.0) ? 1.0f : 0.0f;
        } else spike = (h > 1.0f) ? 1.0f : 0.0f;
        out[(size_t)(row0 + r) * SNN_ROW + n] = spike;
    }
}

extern "C" void kernel_launch(void* const* d_in, const int* in_sizes, int n_in,
                              void* d_out, int out_size, void* d_ws, size_t ws_size,
                              hipStream_t stream) {
    const float* x     = (const float*)d_in[0];
    const float* W_lin = (const float*)d_in[1];
    const float* b_lin = (const float*)d_in[2];
    // d_in[3] (W_sel) and d_in[4] (b_sel) are dead: spk_mode == 0 identically.
    float* out = (float*)d_out;

    if (ws_size >= (size_t)SNN_N * SNN_N * sizeof(float)) {
        float* WT = (float*)d_ws;
        w_transpose_kernel<<<256, 256, 0, stream>>>(W_lin, WT);
        polysnn_main_kernel<<<SNN_B / BLK_ROWS, 256, 0, stream>>>(x, W_lin, WT, b_lin, out);
    } else {
        polysnn_mono_kernel<<<SNN_B / 8, 256, 0, stream>>>(x, W_lin, b_lin, out);
    }
}